// Round 15
// baseline (376.535 us; speedup 1.0000x reference)
//
#include <hip/hip_runtime.h>

#define CMID 32
#define CIN 128
#define HNB 32
#define KP 15
#define NEG 0.1f
#define EPS 1e-5f

// ---------------------------------------------------------------------------
// K1: y1 = s_feats @ w_u1 (M x 128 @ 128 x 32) + bucketed per-channel stats.
// BM=64 -> 782 blocks (3/CU vs 1.5/CU at BM=128): the LDS-GEMM loop is
// latency-exposed, TLP hides it. Per-thread tile 2 rows x 4 cols.
// Stats go to 64 buckets (blockIdx&63) -> ~12 atomic chains/address.
// ---------------------------------------------------------------------------
__global__ __launch_bounds__(256) void k1_gemm1(
    const float* __restrict__ A, const float* __restrict__ B,
    float* __restrict__ y1, float* __restrict__ stb1, int M)
{
    __shared__ __align__(16) float AsT[32 * 64];   // 8 KB [j][row]
    __shared__ __align__(16) float Bs[128 * 32];   // 16 KB
    __shared__ __align__(16) float red[256];
    int t = threadIdx.x;
    for (int i = t; i < 128 * 32; i += 256) Bs[i] = B[i];

    int m0 = blockIdx.x * 64;
    int tx = t & 7, ty = t >> 3;        // cols tx*4, rows ty*2+{0,1}
    int srow = t & 63, sq = t >> 6;     // staging: row, 8-col quarter
    float acc[2][4] = {{0.f}};

    for (int ch = 0; ch < 4; ++ch) {
        __syncthreads();
        int gr = m0 + srow;
        const float4* ap = (const float4*)(A + (size_t)gr * CIN + ch * 32 + sq * 8);
        float4 f0, f1;
        if (gr < M) { f0 = ap[0]; f1 = ap[1]; }
        else { f0 = make_float4(0.f, 0.f, 0.f, 0.f); f1 = f0; }
        int cb = sq * 8;
        AsT[(cb + 0) * 64 + srow] = f0.x;  AsT[(cb + 1) * 64 + srow] = f0.y;
        AsT[(cb + 2) * 64 + srow] = f0.z;  AsT[(cb + 3) * 64 + srow] = f0.w;
        AsT[(cb + 4) * 64 + srow] = f1.x;  AsT[(cb + 5) * 64 + srow] = f1.y;
        AsT[(cb + 6) * 64 + srow] = f1.z;  AsT[(cb + 7) * 64 + srow] = f1.w;
        __syncthreads();
        const float* bsp = Bs + (ch * 32) * 32 + tx * 4;
#pragma unroll
        for (int jl = 0; jl < 32; ++jl) {
            float2 av = *(const float2*)(AsT + jl * 64 + ty * 2);
            float4 bv = *(const float4*)(bsp + jl * 32);
            acc[0][0] += av.x * bv.x; acc[0][1] += av.x * bv.y;
            acc[0][2] += av.x * bv.z; acc[0][3] += av.x * bv.w;
            acc[1][0] += av.y * bv.x; acc[1][1] += av.y * bv.y;
            acc[1][2] += av.y * bv.z; acc[1][3] += av.y * bv.w;
        }
    }
#pragma unroll
    for (int i = 0; i < 2; ++i) {
        int r = m0 + ty * 2 + i;
        if (r < M)
            *(float4*)(y1 + (size_t)r * CMID + tx * 4) =
                make_float4(acc[i][0], acc[i][1], acc[i][2], acc[i][3]);
    }
    // stats (pad rows staged as 0 -> contribute 0)
    float s4[4], q4[4];
#pragma unroll
    for (int e = 0; e < 4; ++e) {
        s4[e] = acc[0][e] + acc[1][e];
        q4[e] = acc[0][e] * acc[0][e] + acc[1][e] * acc[1][e];
    }
#pragma unroll
    for (int off = 8; off <= 32; off <<= 1) {
#pragma unroll
        for (int e = 0; e < 4; ++e) {
            s4[e] += __shfl_xor(s4[e], off);
            q4[e] += __shfl_xor(q4[e], off);
        }
    }
    int lw = t >> 6, ll = t & 63;
    if (ll < 8) {
#pragma unroll
        for (int e = 0; e < 4; ++e) {
            red[(lw * 8 + ll) * 8 + e] = s4[e];
            red[(lw * 8 + ll) * 8 + 4 + e] = q4[e];
        }
    }
    __syncthreads();
    if (t < 64) {
        int tx2 = t >> 3, k = t & 7;
        float v = red[(0 * 8 + tx2) * 8 + k] + red[(1 * 8 + tx2) * 8 + k]
                + red[(2 * 8 + tx2) * 8 + k] + red[(3 * 8 + tx2) * 8 + k];
        int col = tx2 * 4 + (k & 3);
        atomicAdd(&stb1[(size_t)(blockIdx.x & 63) * 64 + (k < 4 ? 0 : 32) + col], v);
    }
}

// ---------------------------------------------------------------------------
// K3: KPInv conv (round-6-verified body) + BUCKETED x2-stats epilogue.
// Round-13 lesson: 6250 blocks x 64 atomics on 64 addrs = ~6250 chains/addr
// cost +100us. 128 buckets -> ~49 chains/addr (k4's 128/addr was free).
// Init sums k1's 64 stat buckets using vbuf/aux as pre-phase scratch.
// ---------------------------------------------------------------------------
__global__ __launch_bounds__(256, 4) void k3_kpinv(
    const float* __restrict__ y1,
    const float* __restrict__ stb1, float* __restrict__ stb2,
    const float* __restrict__ q_pts, const float* __restrict__ s_pts,
    const int* __restrict__ idx, const float* __restrict__ kp,
    const float* __restrict__ g_u1, const float* __restrict__ b_u1,
    const float* __restrict__ w_g1, const float* __restrict__ b_g1,
    const float* __restrict__ w_g2, const float* __restrict__ b_g2,
    float* __restrict__ x2, int M)
{
    __shared__ __align__(16) float a1s[32], b1s[32];
    __shared__ __align__(16) float wg1[32 * 8];
    __shared__ __align__(16) float bg1[8];
    __shared__ __align__(16) float wg2[8 * 30];
    __shared__ __align__(16) float bg2[32];
    __shared__ __align__(16) float kps[KP * 3 + 1];
    __shared__ __align__(16) float vbuf[4][2][1024];
    __shared__ __align__(16) float aux[4][2][144];

    int t = threadIdx.x;
    // ---- init: sum k1's 64 stat buckets -> a1s/b1s (scratch: vbuf, aux) ----
    {
        float* tmp = &vbuf[0][0][0];     // 256 floats, pre-phase-1 scratch
        int entry = t & 63, qd = t >> 6;
        float ps = 0.f;
        for (int b = qd * 16; b < qd * 16 + 16; ++b)
            ps += stb1[(size_t)b * 64 + entry];
        tmp[t] = ps;
        __syncthreads();
        if (t < 64)
            aux[0][0][t] = tmp[t] + tmp[64 + t] + tmp[128 + t] + tmp[192 + t];
        __syncthreads();
        if (t < 32) {
            float mean = aux[0][0][t] * (1.0f / M);
            float var  = aux[0][0][32 + t] * (1.0f / M) - mean * mean;
            float inv  = rsqrtf(var + EPS);
            float a = g_u1[t] * inv;
            a1s[t] = a;
            b1s[t] = b_u1[t] - mean * a;
        }
    }
    wg1[t & 255] = w_g1[t & 255];
    if (t < 8)   bg1[t] = b_g1[t];
    if (t < 240) wg2[t] = w_g2[t];
    if (t < 30)  bg2[t] = b_g2[t];
    else if (t < 32) bg2[t] = 0.f;
    if (t < KP * 3) kps[t] = kp[t];
    __syncthreads();

    int wave = t >> 6, lane = t & 63;
    int p = lane >> 5;
    int q = lane & 31;
    int m = blockIdx.x * 8 + wave * 2 + p;
    bool valid = (m < M);
    int mm = valid ? m : 0;
    float* vb = &vbuf[wave][p][0];
    float* ax = &aux[wave][p][0];
    float osum = 0.f;

    // ---------------- Phase 1: q = h ----------------
    int h = q;
    int n = idx[(size_t)mm * HNB + h];
    float qx = q_pts[mm * 3 + 0], qy = q_pts[mm * 3 + 1], qz = q_pts[mm * 3 + 2];
    float dx = s_pts[n * 3 + 0] - qx;
    float dy = s_pts[n * 3 + 1] - qy;
    float dz = s_pts[n * 3 + 2] - qz;

    float infl[KP];
#pragma unroll
    for (int k = 0; k < KP; ++k) {
        float ex = dx - kps[k * 3 + 0];
        float ey = dy - kps[k * 3 + 1];
        float ez = dz - kps[k * 3 + 2];
        float d = sqrtf(ex * ex + ey * ey + ez * ez);
        infl[k] = fmaxf(1.0f - d, 0.f);
    }

    {
        const float4* row = (const float4*)(y1 + (size_t)n * CMID);
        int hq4 = h >> 2, h3 = h & 3;
#pragma unroll
        for (int jj = 0; jj < 8; ++jj) {
            float4 f = row[jj];
            float vv[4] = {f.x, f.y, f.z, f.w};
#pragma unroll
            for (int e = 0; e < 4; ++e) {
                int c = jj * 4 + e;
                float x = vv[e] * a1s[c] + b1s[c];
                x = fmaxf(x, NEG * x);
                vb[(c << 5) + ((hq4 ^ (c & 7)) << 2) + h3] = x;
            }
        }
    }
    __builtin_amdgcn_wave_barrier();

    // ---------------- Phase 2: q = c ----------------
    {
        int c = q;
        int c7 = c & 7;
        const float* vrow = vb + (c << 5);
        float cm = -1e30f;
#pragma unroll
        for (int j = 0; j < 8; ++j) {
            const float4 f = *(const float4*)(vrow + ((j ^ c7) << 2));
            cm = fmaxf(fmaxf(fmaxf(cm, f.x), fmaxf(f.y, f.z)), f.w);
        }
        ax[c] = cm;
        __builtin_amdgcn_wave_barrier();

        int jm = c & 7;
        float acc = bg1[jm];
#pragma unroll
        for (int cc = 0; cc < 8; ++cc) {
            const float4 ce = *(const float4*)(ax + (cc << 2));
            acc += ce.x * wg1[(cc * 4 + 0) * 8 + jm];
            acc += ce.y * wg1[(cc * 4 + 1) * 8 + jm];
            acc += ce.z * wg1[(cc * 4 + 2) * 8 + jm];
            acc += ce.w * wg1[(cc * 4 + 3) * 8 + jm];
        }
        float h1v = fmaxf(acc, NEG * acc);
        if (c < 8) ax[32 + c] = h1v;
        __builtin_amdgcn_wave_barrier();

        float wv = 0.f;
        if (c < 30) {
            const float4 ha = *(const float4*)(ax + 32);
            const float4 hb = *(const float4*)(ax + 36);
            wv = bg2[c]
               + ha.x * wg2[0 * 30 + c] + ha.y * wg2[1 * 30 + c]
               + ha.z * wg2[2 * 30 + c] + ha.w * wg2[3 * 30 + c]
               + hb.x * wg2[4 * 30 + c] + hb.y * wg2[5 * 30 + c]
               + hb.z * wg2[6 * 30 + c] + hb.w * wg2[7 * 30 + c];
        }
        ax[40 + c] = wv;
    }
    __builtin_amdgcn_wave_barrier();

    // ---------------- Phase 3: q = h ----------------
    {
        float wf[32];
#pragma unroll
        for (int j = 0; j < 8; ++j) {
            const float4 wc = *(const float4*)(ax + 40 + (j << 2));
            wf[j * 4 + 0] = wc.x; wf[j * 4 + 1] = wc.y;
            wf[j * 4 + 2] = wc.z; wf[j * 4 + 3] = wc.w;
        }
        float s0 = 0.f, s1 = 0.f;
#pragma unroll
        for (int k = 0; k < KP; ++k) {
            s0 += infl[k] * wf[2 * k + 0];
            s1 += infl[k] * wf[2 * k + 1];
        }
        ax[72 + q]  = s0;
        ax[104 + q] = s1;
    }
    __builtin_amdgcn_wave_barrier();

    // ---------------- Phase 4: q = c ----------------
    {
        int c = q;
        int c7 = c & 7;
        const float* sbuf = ax + 72 + ((c >> 4) << 5);
        const float* vrow = vb + (c << 5);
        float o = 0.f;
#pragma unroll
        for (int j = 0; j < 8; ++j) {
            const float4 vv = *(const float4*)(vrow + ((j ^ c7) << 2));
            const float4 ss = *(const float4*)(sbuf + (j << 2));
            o += vv.x * ss.x + vv.y * ss.y + vv.z * ss.z + vv.w * ss.w;
        }
        if (valid) {
            x2[(size_t)m * CMID + c] = o;
            osum = o;
        }
    }

    // ---- epilogue: bucketed x2 stats (replaces k4) ----
    __syncthreads();                   // all waves done with vbuf
    float* red = &vbuf[0][0][0];
    float* bkt = stb2 + (size_t)(blockIdx.x & 127) * 64;
    red[t] = osum;
    __syncthreads();
    if (t < 32) {
        float s = 0.f;
#pragma unroll
        for (int i = 0; i < 8; ++i) s += red[t + 32 * i];
        atomicAdd(&bkt[t], s);
    }
    __syncthreads();
    red[t] = osum * osum;
    __syncthreads();
    if (t < 32) {
        float s = 0.f;
#pragma unroll
        for (int i = 0; i < 8; ++i) s += red[t + 32 * i];
        atomicAdd(&bkt[32 + t], s);
    }
}

// ---------------------------------------------------------------------------
// K6: z = lrelu(bn_c(x2)) @ w_u2; z -> out (scratch), z-stats -> st[128:384).
// Init sums k3's 128 x2-stat buckets (replaces k4's output).
// ---------------------------------------------------------------------------
__global__ __launch_bounds__(256) void k6_zstats(
    const float* __restrict__ x2, const float* __restrict__ w_u2,
    const float* __restrict__ g_c, const float* __restrict__ b_c,
    const float* __restrict__ stb2, float* __restrict__ st,
    float* __restrict__ zout, int M)
{
    __shared__ __align__(16) float ST[32 * 128];
    __shared__ __align__(16) float Ws[32 * 32];
    __shared__ __align__(16) float acs[32], bcs[32];
    __shared__ __align__(16) float red[256];
    int t = threadIdx.x;
    int cb = blockIdx.y;
    int m0 = blockIdx.x * 128;
    for (int i = t; i < 32 * 32; i += 256)
        Ws[i] = w_u2[(i >> 5) * CIN + cb * 32 + (i & 31)];
    // ---- init: sum the 128 x2-stat buckets -> acs/bcs ----
    {
        int entry = t & 63, qd = t >> 6;
        float ps = 0.f;
        for (int b = qd * 32; b < qd * 32 + 32; ++b)
            ps += stb2[(size_t)b * 64 + entry];
        red[t] = ps;
        __syncthreads();
        if (t < 64)
            red[t] = red[t] + red[64 + t] + red[128 + t] + red[192 + t];
        __syncthreads();
        if (t < 32) {
            float mean = red[t] * (1.0f / M);
            float var  = red[32 + t] * (1.0f / M) - mean * mean;
            float inv  = rsqrtf(var + EPS);
            float a = g_c[t] * inv;
            acs[t] = a; bcs[t] = b_c[t] - mean * a;
        }
    }
    __syncthreads();

    int srow = t & 127, shh = t >> 7;
    int gr = m0 + srow;
    const float4* xp = (const float4*)(x2 + (size_t)gr * CMID + shh * 16);
    float4 f0, f1, f2, f3;
    if (gr < M) { f0 = xp[0]; f1 = xp[1]; f2 = xp[2]; f3 = xp[3]; }
    else { f0 = f1 = f2 = f3 = make_float4(0.f, 0.f, 0.f, 0.f); }
    {
        float vv[16] = {f0.x, f0.y, f0.z, f0.w, f1.x, f1.y, f1.z, f1.w,
                        f2.x, f2.y, f2.z, f2.w, f3.x, f3.y, f3.z, f3.w};
        int cbse = shh * 16;
#pragma unroll
        for (int e = 0; e < 16; ++e) {
            int c = cbse + e;
            float x = vv[e] * acs[c] + bcs[c];
            x = fmaxf(x, NEG * x);
            ST[c * 128 + srow] = (gr < M) ? x : 0.f;
        }
    }
    __syncthreads();

    int tx = t & 7, ty = t >> 3;
    float acc[4][4] = {{0.f}};
#pragma unroll
    for (int j = 0; j < 32; ++j) {
        float4 av = *(const float4*)(ST + j * 128 + ty * 4);
        float4 bv = *(const float4*)(Ws + j * 32 + tx * 4);
        acc[0][0] += av.x * bv.x; acc[0][1] += av.x * bv.y; acc[0][2] += av.x * bv.z; acc[0][3] += av.x * bv.w;
        acc[1][0] += av.y * bv.x; acc[1][1] += av.y * bv.y; acc[1][2] += av.y * bv.z; acc[1][3] += av.y * bv.w;
        acc[2][0] += av.z * bv.x; acc[2][1] += av.z * bv.y; acc[2][2] += av.z * bv.z; acc[2][3] += av.z * bv.w;
        acc[3][0] += av.w * bv.x; acc[3][1] += av.w * bv.y; acc[3][2] += av.w * bv.z; acc[3][3] += av.w * bv.w;
    }
    // store z (scratch in out buffer)
#pragma unroll
    for (int i = 0; i < 4; ++i) {
        int r = m0 + ty * 4 + i;
        if (r < M)
            *(float4*)(zout + (size_t)r * CIN + cb * 32 + tx * 4) =
                make_float4(acc[i][0], acc[i][1], acc[i][2], acc[i][3]);
    }
    // z-stats (plain atomics: 1564 blocks / 256 addrs = ~6 chains/addr, fine)
    float s4[4], q4[4];
#pragma unroll
    for (int e = 0; e < 4; ++e) {
        s4[e] = acc[0][e] + acc[1][e] + acc[2][e] + acc[3][e];
        q4[e] = acc[0][e] * acc[0][e] + acc[1][e] * acc[1][e]
              + acc[2][e] * acc[2][e] + acc[3][e] * acc[3][e];
    }
#pragma unroll
    for (int off = 8; off <= 32; off <<= 1) {
#pragma unroll
        for (int e = 0; e < 4; ++e) {
            s4[e] += __shfl_xor(s4[e], off);
            q4[e] += __shfl_xor(q4[e], off);
        }
    }
    int lw = t >> 6, ll = t & 63;
    if (ll < 8) {
#pragma unroll
        for (int e = 0; e < 4; ++e) {
            red[(lw * 8 + ll) * 8 + e] = s4[e];
            red[(lw * 8 + ll) * 8 + 4 + e] = q4[e];
        }
    }
    __syncthreads();
    if (t < 64) {
        int tx2 = t >> 3, k = t & 7;
        float v = red[(0 * 8 + tx2) * 8 + k] + red[(1 * 8 + tx2) * 8 + k]
                + red[(2 * 8 + tx2) * 8 + k] + red[(3 * 8 + tx2) * 8 + k];
        int col = cb * 32 + tx2 * 4 + (k & 3);
        atomicAdd(&st[(k < 4 ? 128 : 256) + col], v);
    }
}

// ---------------------------------------------------------------------------
// K8: elementwise final. z in out (scratch): out = lrelu(z*a2+b2 + s_feats).
// ---------------------------------------------------------------------------
__global__ __launch_bounds__(256) void k8_elem(
    const float* __restrict__ s_feats,
    const float* __restrict__ g_u2, const float* __restrict__ b_u2,
    const float* __restrict__ st, float* __restrict__ out, int M)
{
    __shared__ float a2s[128], b2s[128];
    int t = threadIdx.x;
    if (t < 128) {
        float mean = st[128 + t] * (1.0f / M);
        float var  = st[256 + t] * (1.0f / M) - mean * mean;
        float inv  = rsqrtf(var + EPS);
        float a = g_u2[t] * inv;
        a2s[t] = a; b2s[t] = b_u2[t] - mean * a;
    }
    __syncthreads();
    size_t total = (size_t)M * 32;   // float4 count
    float4* o4 = (float4*)out;
    const float4* s4 = (const float4*)s_feats;
    for (size_t i = (size_t)blockIdx.x * 256 + t; i < total;
         i += (size_t)gridDim.x * 256) {
        float4 z = o4[i];
        float4 sf = s4[i];
        int c = ((int)(i & 31)) * 4;
        float v0 = z.x * a2s[c + 0] + b2s[c + 0] + sf.x;
        float v1 = z.y * a2s[c + 1] + b2s[c + 1] + sf.y;
        float v2 = z.z * a2s[c + 2] + b2s[c + 2] + sf.z;
        float v3 = z.w * a2s[c + 3] + b2s[c + 3] + sf.w;
        v0 = fmaxf(v0, NEG * v0); v1 = fmaxf(v1, NEG * v1);
        v2 = fmaxf(v2, NEG * v2); v3 = fmaxf(v3, NEG * v3);
        o4[i] = make_float4(v0, v1, v2, v3);
    }
}

extern "C" void kernel_launch(void* const* d_in, const int* in_sizes, int n_in,
                              void* d_out, int out_size, void* d_ws, size_t ws_size,
                              hipStream_t stream) {
    const float* q_pts   = (const float*)d_in[0];
    const float* s_pts   = (const float*)d_in[1];
    const float* s_feats = (const float*)d_in[2];
    const int*   idx     = (const int*)d_in[3];
    const float* kp      = (const float*)d_in[4];
    const float* w_u1    = (const float*)d_in[5];
    const float* g_u1    = (const float*)d_in[6];
    const float* b_u1    = (const float*)d_in[7];
    const float* w_g1    = (const float*)d_in[8];
    const float* b_g1    = (const float*)d_in[9];
    const float* w_g2    = (const float*)d_in[10];
    const float* b_g2    = (const float*)d_in[11];
    const float* g_c     = (const float*)d_in[12];
    const float* b_c     = (const float*)d_in[13];
    const float* w_u2    = (const float*)d_in[14];
    const float* g_u2    = (const float*)d_in[15];
    const float* b_u2    = (const float*)d_in[16];

    int M = in_sizes[3] / HNB;   // 50000

    float* ws = (float*)d_ws;
    float* y1  = ws;                         // M*32
    float* x2  = ws + (size_t)M * CMID;      // M*32
    float* st  = ws + (size_t)M * 2 * CMID;  // 384 (z-stats at [128:384))
    float* stb1 = st + 384;                  // 64 buckets x 64 (y1 stats)
    float* stb2 = stb1 + 64 * 64;            // 128 buckets x 64 (x2 stats)
    float* out = (float*)d_out;

    hipMemsetAsync(st, 0, (384 + 64 * 64 + 128 * 64) * sizeof(float), stream);

    int nb64 = (M + 63) / 64;     // 782 (k1)
    int nbr  = (M + 127) / 128;   // 391 (k6)
    k1_gemm1<<<nb64, 256, 0, stream>>>(s_feats, w_u1, y1, stb1, M);
    k3_kpinv<<<(M + 7) / 8, 256, 0, stream>>>(y1, stb1, stb2, q_pts, s_pts, idx, kp,
                                              g_u1, b_u1, w_g1, b_g1, w_g2, b_g2,
                                              x2, M);
    k6_zstats<<<dim3(nbr, 4), 256, 0, stream>>>(x2, w_u2, g_c, b_c, stb2, st, out, M);
    k8_elem<<<2048, 256, 0, stream>>>(s_feats, g_u2, b_u2, st, out, M);
}

// Round 16
// 232.760 us; speedup vs baseline: 1.6177x; 1.6177x over previous
//
#include <hip/hip_runtime.h>

#define CMID 32
#define CIN 128
#define HNB 32
#define KP 15
#define NEG 0.1f
#define EPS 1e-5f

// ---------------------------------------------------------------------------
// K1: y1 = s_feats @ w_u1 (M x 128 @ 128 x 32) + bucketed per-channel stats.
// ROUND-6-VERIFIED BM=128 BODY (round-15's BM=64 retile spilled: VGPR 256,
// 204MB scratch WRITE, 170us). Only change vs round-6: stats write to the
// stb1 bucket (blockIdx&63) that k3's init sums.
// ---------------------------------------------------------------------------
__global__ __launch_bounds__(256) void k1_gemm1(
    const float* __restrict__ A, const float* __restrict__ B,
    float* __restrict__ y1, float* __restrict__ stb1, int M)
{
    __shared__ __align__(16) float AsT[32 * 128];  // 16 KB [j][row]
    __shared__ __align__(16) float Bs[128 * 32];   // 16 KB
    __shared__ __align__(16) float red[256];
    int t = threadIdx.x;
    for (int i = t; i < 128 * 32; i += 256) Bs[i] = B[i];

    int m0 = blockIdx.x * 128;
    int tx = t & 7, ty = t >> 3;
    int srow = t & 127, shh = t >> 7;
    float acc[4][4] = {{0.f}};

    for (int ch = 0; ch < 4; ++ch) {
        __syncthreads();
        int gr = m0 + srow;
        const float4* ap = (const float4*)(A + (size_t)gr * CIN + ch * 32 + shh * 16);
        float4 f0, f1, f2, f3;
        if (gr < M) { f0 = ap[0]; f1 = ap[1]; f2 = ap[2]; f3 = ap[3]; }
        else { f0 = f1 = f2 = f3 = make_float4(0.f, 0.f, 0.f, 0.f); }
        {
            int cb = shh * 16;
            AsT[(cb + 0) * 128 + srow] = f0.x;  AsT[(cb + 1) * 128 + srow] = f0.y;
            AsT[(cb + 2) * 128 + srow] = f0.z;  AsT[(cb + 3) * 128 + srow] = f0.w;
            AsT[(cb + 4) * 128 + srow] = f1.x;  AsT[(cb + 5) * 128 + srow] = f1.y;
            AsT[(cb + 6) * 128 + srow] = f1.z;  AsT[(cb + 7) * 128 + srow] = f1.w;
            AsT[(cb + 8) * 128 + srow] = f2.x;  AsT[(cb + 9) * 128 + srow] = f2.y;
            AsT[(cb + 10) * 128 + srow] = f2.z; AsT[(cb + 11) * 128 + srow] = f2.w;
            AsT[(cb + 12) * 128 + srow] = f3.x; AsT[(cb + 13) * 128 + srow] = f3.y;
            AsT[(cb + 14) * 128 + srow] = f3.z; AsT[(cb + 15) * 128 + srow] = f3.w;
        }
        __syncthreads();
        const float* bsp = Bs + (ch * 32) * 32 + tx * 4;
#pragma unroll
        for (int jl = 0; jl < 32; ++jl) {
            float4 av = *(const float4*)(AsT + jl * 128 + ty * 4);
            float4 bv = *(const float4*)(bsp + jl * 32);
            acc[0][0] += av.x * bv.x; acc[0][1] += av.x * bv.y; acc[0][2] += av.x * bv.z; acc[0][3] += av.x * bv.w;
            acc[1][0] += av.y * bv.x; acc[1][1] += av.y * bv.y; acc[1][2] += av.y * bv.z; acc[1][3] += av.y * bv.w;
            acc[2][0] += av.z * bv.x; acc[2][1] += av.z * bv.y; acc[2][2] += av.z * bv.z; acc[2][3] += av.z * bv.w;
            acc[3][0] += av.w * bv.x; acc[3][1] += av.w * bv.y; acc[3][2] += av.w * bv.z; acc[3][3] += av.w * bv.w;
        }
    }
#pragma unroll
    for (int i = 0; i < 4; ++i) {
        int r = m0 + ty * 4 + i;
        if (r < M)
            *(float4*)(y1 + (size_t)r * CMID + tx * 4) =
                make_float4(acc[i][0], acc[i][1], acc[i][2], acc[i][3]);
    }
    float s4[4], q4[4];
#pragma unroll
    for (int e = 0; e < 4; ++e) {
        s4[e] = acc[0][e] + acc[1][e] + acc[2][e] + acc[3][e];
        q4[e] = acc[0][e] * acc[0][e] + acc[1][e] * acc[1][e]
              + acc[2][e] * acc[2][e] + acc[3][e] * acc[3][e];
    }
#pragma unroll
    for (int off = 8; off <= 32; off <<= 1) {
#pragma unroll
        for (int e = 0; e < 4; ++e) {
            s4[e] += __shfl_xor(s4[e], off);
            q4[e] += __shfl_xor(q4[e], off);
        }
    }
    int lw = t >> 6, ll = t & 63;
    if (ll < 8) {
#pragma unroll
        for (int e = 0; e < 4; ++e) {
            red[(lw * 8 + ll) * 8 + e] = s4[e];
            red[(lw * 8 + ll) * 8 + 4 + e] = q4[e];
        }
    }
    __syncthreads();
    if (t < 64) {
        int tx2 = t >> 3, k = t & 7;
        float v = red[(0 * 8 + tx2) * 8 + k] + red[(1 * 8 + tx2) * 8 + k]
                + red[(2 * 8 + tx2) * 8 + k] + red[(3 * 8 + tx2) * 8 + k];
        int col = tx2 * 4 + (k & 3);
        atomicAdd(&stb1[(size_t)(blockIdx.x & 63) * 64 + (k < 4 ? 0 : 32) + col], v);
    }
}

// ---------------------------------------------------------------------------
// K3: KPInv conv (round-6-verified body) + BUCKETED x2-stats epilogue
// (round-15 measured: bucketing net -16us vs separate k4).
// Init sums k1's 64 stat buckets using vbuf/aux as pre-phase scratch.
// ---------------------------------------------------------------------------
__global__ __launch_bounds__(256, 4) void k3_kpinv(
    const float* __restrict__ y1,
    const float* __restrict__ stb1, float* __restrict__ stb2,
    const float* __restrict__ q_pts, const float* __restrict__ s_pts,
    const int* __restrict__ idx, const float* __restrict__ kp,
    const float* __restrict__ g_u1, const float* __restrict__ b_u1,
    const float* __restrict__ w_g1, const float* __restrict__ b_g1,
    const float* __restrict__ w_g2, const float* __restrict__ b_g2,
    float* __restrict__ x2, int M)
{
    __shared__ __align__(16) float a1s[32], b1s[32];
    __shared__ __align__(16) float wg1[32 * 8];
    __shared__ __align__(16) float bg1[8];
    __shared__ __align__(16) float wg2[8 * 30];
    __shared__ __align__(16) float bg2[32];
    __shared__ __align__(16) float kps[KP * 3 + 1];
    __shared__ __align__(16) float vbuf[4][2][1024];
    __shared__ __align__(16) float aux[4][2][144];

    int t = threadIdx.x;
    // ---- init: sum k1's 64 stat buckets -> a1s/b1s (scratch: vbuf, aux) ----
    {
        float* tmp = &vbuf[0][0][0];     // 256 floats, pre-phase-1 scratch
        int entry = t & 63, qd = t >> 6;
        float ps = 0.f;
        for (int b = qd * 16; b < qd * 16 + 16; ++b)
            ps += stb1[(size_t)b * 64 + entry];
        tmp[t] = ps;
        __syncthreads();
        if (t < 64)
            aux[0][0][t] = tmp[t] + tmp[64 + t] + tmp[128 + t] + tmp[192 + t];
        __syncthreads();
        if (t < 32) {
            float mean = aux[0][0][t] * (1.0f / M);
            float var  = aux[0][0][32 + t] * (1.0f / M) - mean * mean;
            float inv  = rsqrtf(var + EPS);
            float a = g_u1[t] * inv;
            a1s[t] = a;
            b1s[t] = b_u1[t] - mean * a;
        }
    }
    wg1[t & 255] = w_g1[t & 255];
    if (t < 8)   bg1[t] = b_g1[t];
    if (t < 240) wg2[t] = w_g2[t];
    if (t < 30)  bg2[t] = b_g2[t];
    else if (t < 32) bg2[t] = 0.f;
    if (t < KP * 3) kps[t] = kp[t];
    __syncthreads();

    int wave = t >> 6, lane = t & 63;
    int p = lane >> 5;
    int q = lane & 31;
    int m = blockIdx.x * 8 + wave * 2 + p;
    bool valid = (m < M);
    int mm = valid ? m : 0;
    float* vb = &vbuf[wave][p][0];
    float* ax = &aux[wave][p][0];
    float osum = 0.f;

    // ---------------- Phase 1: q = h ----------------
    int h = q;
    int n = idx[(size_t)mm * HNB + h];
    float qx = q_pts[mm * 3 + 0], qy = q_pts[mm * 3 + 1], qz = q_pts[mm * 3 + 2];
    float dx = s_pts[n * 3 + 0] - qx;
    float dy = s_pts[n * 3 + 1] - qy;
    float dz = s_pts[n * 3 + 2] - qz;

    float infl[KP];
#pragma unroll
    for (int k = 0; k < KP; ++k) {
        float ex = dx - kps[k * 3 + 0];
        float ey = dy - kps[k * 3 + 1];
        float ez = dz - kps[k * 3 + 2];
        float d = sqrtf(ex * ex + ey * ey + ez * ez);
        infl[k] = fmaxf(1.0f - d, 0.f);
    }

    {
        const float4* row = (const float4*)(y1 + (size_t)n * CMID);
        int hq4 = h >> 2, h3 = h & 3;
#pragma unroll
        for (int jj = 0; jj < 8; ++jj) {
            float4 f = row[jj];
            float vv[4] = {f.x, f.y, f.z, f.w};
#pragma unroll
            for (int e = 0; e < 4; ++e) {
                int c = jj * 4 + e;
                float x = vv[e] * a1s[c] + b1s[c];
                x = fmaxf(x, NEG * x);
                vb[(c << 5) + ((hq4 ^ (c & 7)) << 2) + h3] = x;
            }
        }
    }
    __builtin_amdgcn_wave_barrier();

    // ---------------- Phase 2: q = c ----------------
    {
        int c = q;
        int c7 = c & 7;
        const float* vrow = vb + (c << 5);
        float cm = -1e30f;
#pragma unroll
        for (int j = 0; j < 8; ++j) {
            const float4 f = *(const float4*)(vrow + ((j ^ c7) << 2));
            cm = fmaxf(fmaxf(fmaxf(cm, f.x), fmaxf(f.y, f.z)), f.w);
        }
        ax[c] = cm;
        __builtin_amdgcn_wave_barrier();

        int jm = c & 7;
        float acc = bg1[jm];
#pragma unroll
        for (int cc = 0; cc < 8; ++cc) {
            const float4 ce = *(const float4*)(ax + (cc << 2));
            acc += ce.x * wg1[(cc * 4 + 0) * 8 + jm];
            acc += ce.y * wg1[(cc * 4 + 1) * 8 + jm];
            acc += ce.z * wg1[(cc * 4 + 2) * 8 + jm];
            acc += ce.w * wg1[(cc * 4 + 3) * 8 + jm];
        }
        float h1v = fmaxf(acc, NEG * acc);
        if (c < 8) ax[32 + c] = h1v;
        __builtin_amdgcn_wave_barrier();

        float wv = 0.f;
        if (c < 30) {
            const float4 ha = *(const float4*)(ax + 32);
            const float4 hb = *(const float4*)(ax + 36);
            wv = bg2[c]
               + ha.x * wg2[0 * 30 + c] + ha.y * wg2[1 * 30 + c]
               + ha.z * wg2[2 * 30 + c] + ha.w * wg2[3 * 30 + c]
               + hb.x * wg2[4 * 30 + c] + hb.y * wg2[5 * 30 + c]
               + hb.z * wg2[6 * 30 + c] + hb.w * wg2[7 * 30 + c];
        }
        ax[40 + c] = wv;
    }
    __builtin_amdgcn_wave_barrier();

    // ---------------- Phase 3: q = h ----------------
    {
        float wf[32];
#pragma unroll
        for (int j = 0; j < 8; ++j) {
            const float4 wc = *(const float4*)(ax + 40 + (j << 2));
            wf[j * 4 + 0] = wc.x; wf[j * 4 + 1] = wc.y;
            wf[j * 4 + 2] = wc.z; wf[j * 4 + 3] = wc.w;
        }
        float s0 = 0.f, s1 = 0.f;
#pragma unroll
        for (int k = 0; k < KP; ++k) {
            s0 += infl[k] * wf[2 * k + 0];
            s1 += infl[k] * wf[2 * k + 1];
        }
        ax[72 + q]  = s0;
        ax[104 + q] = s1;
    }
    __builtin_amdgcn_wave_barrier();

    // ---------------- Phase 4: q = c ----------------
    {
        int c = q;
        int c7 = c & 7;
        const float* sbuf = ax + 72 + ((c >> 4) << 5);
        const float* vrow = vb + (c << 5);
        float o = 0.f;
#pragma unroll
        for (int j = 0; j < 8; ++j) {
            const float4 vv = *(const float4*)(vrow + ((j ^ c7) << 2));
            const float4 ss = *(const float4*)(sbuf + (j << 2));
            o += vv.x * ss.x + vv.y * ss.y + vv.z * ss.z + vv.w * ss.w;
        }
        if (valid) {
            x2[(size_t)m * CMID + c] = o;
            osum = o;
        }
    }

    // ---- epilogue: bucketed x2 stats (replaces k4; round-15 verified) ----
    __syncthreads();                   // all waves done with vbuf
    float* red = &vbuf[0][0][0];
    float* bkt = stb2 + (size_t)(blockIdx.x & 127) * 64;
    red[t] = osum;
    __syncthreads();
    if (t < 32) {
        float s = 0.f;
#pragma unroll
        for (int i = 0; i < 8; ++i) s += red[t + 32 * i];
        atomicAdd(&bkt[t], s);
    }
    __syncthreads();
    red[t] = osum * osum;
    __syncthreads();
    if (t < 32) {
        float s = 0.f;
#pragma unroll
        for (int i = 0; i < 8; ++i) s += red[t + 32 * i];
        atomicAdd(&bkt[32 + t], s);
    }
}

// ---------------------------------------------------------------------------
// K6: z = lrelu(bn_c(x2)) @ w_u2; z -> out (scratch), z-stats -> st[128:384).
// Init sums k3's 128 x2-stat buckets (round-15 verified).
// ---------------------------------------------------------------------------
__global__ __launch_bounds__(256) void k6_zstats(
    const float* __restrict__ x2, const float* __restrict__ w_u2,
    const float* __restrict__ g_c, const float* __restrict__ b_c,
    const float* __restrict__ stb2, float* __restrict__ st,
    float* __restrict__ zout, int M)
{
    __shared__ __align__(16) float ST[32 * 128];
    __shared__ __align__(16) float Ws[32 * 32];
    __shared__ __align__(16) float acs[32], bcs[32];
    __shared__ __align__(16) float red[256];
    int t = threadIdx.x;
    int cb = blockIdx.y;
    int m0 = blockIdx.x * 128;
    for (int i = t; i < 32 * 32; i += 256)
        Ws[i] = w_u2[(i >> 5) * CIN + cb * 32 + (i & 31)];
    // ---- init: sum the 128 x2-stat buckets -> acs/bcs ----
    {
        int entry = t & 63, qd = t >> 6;
        float ps = 0.f;
        for (int b = qd * 32; b < qd * 32 + 32; ++b)
            ps += stb2[(size_t)b * 64 + entry];
        red[t] = ps;
        __syncthreads();
        if (t < 64)
            red[t] = red[t] + red[64 + t] + red[128 + t] + red[192 + t];
        __syncthreads();
        if (t < 32) {
            float mean = red[t] * (1.0f / M);
            float var  = red[32 + t] * (1.0f / M) - mean * mean;
            float inv  = rsqrtf(var + EPS);
            float a = g_c[t] * inv;
            acs[t] = a; bcs[t] = b_c[t] - mean * a;
        }
    }
    __syncthreads();

    int srow = t & 127, shh = t >> 7;
    int gr = m0 + srow;
    const float4* xp = (const float4*)(x2 + (size_t)gr * CMID + shh * 16);
    float4 f0, f1, f2, f3;
    if (gr < M) { f0 = xp[0]; f1 = xp[1]; f2 = xp[2]; f3 = xp[3]; }
    else { f0 = f1 = f2 = f3 = make_float4(0.f, 0.f, 0.f, 0.f); }
    {
        float vv[16] = {f0.x, f0.y, f0.z, f0.w, f1.x, f1.y, f1.z, f1.w,
                        f2.x, f2.y, f2.z, f2.w, f3.x, f3.y, f3.z, f3.w};
        int cbse = shh * 16;
#pragma unroll
        for (int e = 0; e < 16; ++e) {
            int c = cbse + e;
            float x = vv[e] * acs[c] + bcs[c];
            x = fmaxf(x, NEG * x);
            ST[c * 128 + srow] = (gr < M) ? x : 0.f;
        }
    }
    __syncthreads();

    int tx = t & 7, ty = t >> 3;
    float acc[4][4] = {{0.f}};
#pragma unroll
    for (int j = 0; j < 32; ++j) {
        float4 av = *(const float4*)(ST + j * 128 + ty * 4);
        float4 bv = *(const float4*)(Ws + j * 32 + tx * 4);
        acc[0][0] += av.x * bv.x; acc[0][1] += av.x * bv.y; acc[0][2] += av.x * bv.z; acc[0][3] += av.x * bv.w;
        acc[1][0] += av.y * bv.x; acc[1][1] += av.y * bv.y; acc[1][2] += av.y * bv.z; acc[1][3] += av.y * bv.w;
        acc[2][0] += av.z * bv.x; acc[2][1] += av.z * bv.y; acc[2][2] += av.z * bv.z; acc[2][3] += av.z * bv.w;
        acc[3][0] += av.w * bv.x; acc[3][1] += av.w * bv.y; acc[3][2] += av.w * bv.z; acc[3][3] += av.w * bv.w;
    }
    // store z (scratch in out buffer)
#pragma unroll
    for (int i = 0; i < 4; ++i) {
        int r = m0 + ty * 4 + i;
        if (r < M)
            *(float4*)(zout + (size_t)r * CIN + cb * 32 + tx * 4) =
                make_float4(acc[i][0], acc[i][1], acc[i][2], acc[i][3]);
    }
    // z-stats (plain atomics: 1564 blocks / 256 addrs = ~6 chains/addr, fine)
    float s4[4], q4[4];
#pragma unroll
    for (int e = 0; e < 4; ++e) {
        s4[e] = acc[0][e] + acc[1][e] + acc[2][e] + acc[3][e];
        q4[e] = acc[0][e] * acc[0][e] + acc[1][e] * acc[1][e]
              + acc[2][e] * acc[2][e] + acc[3][e] * acc[3][e];
    }
#pragma unroll
    for (int off = 8; off <= 32; off <<= 1) {
#pragma unroll
        for (int e = 0; e < 4; ++e) {
            s4[e] += __shfl_xor(s4[e], off);
            q4[e] += __shfl_xor(q4[e], off);
        }
    }
    int lw = t >> 6, ll = t & 63;
    if (ll < 8) {
#pragma unroll
        for (int e = 0; e < 4; ++e) {
            red[(lw * 8 + ll) * 8 + e] = s4[e];
            red[(lw * 8 + ll) * 8 + 4 + e] = q4[e];
        }
    }
    __syncthreads();
    if (t < 64) {
        int tx2 = t >> 3, k = t & 7;
        float v = red[(0 * 8 + tx2) * 8 + k] + red[(1 * 8 + tx2) * 8 + k]
                + red[(2 * 8 + tx2) * 8 + k] + red[(3 * 8 + tx2) * 8 + k];
        int col = cb * 32 + tx2 * 4 + (k & 3);
        atomicAdd(&st[(k < 4 ? 128 : 256) + col], v);
    }
}

// ---------------------------------------------------------------------------
// K8: elementwise final. z in out (scratch): out = lrelu(z*a2+b2 + s_feats).
// ---------------------------------------------------------------------------
__global__ __launch_bounds__(256) void k8_elem(
    const float* __restrict__ s_feats,
    const float* __restrict__ g_u2, const float* __restrict__ b_u2,
    const float* __restrict__ st, float* __restrict__ out, int M)
{
    __shared__ float a2s[128], b2s[128];
    int t = threadIdx.x;
    if (t < 128) {
        float mean = st[128 + t] * (1.0f / M);
        float var  = st[256 + t] * (1.0f / M) - mean * mean;
        float inv  = rsqrtf(var + EPS);
        float a = g_u2[t] * inv;
        a2s[t] = a; b2s[t] = b_u2[t] - mean * a;
    }
    __syncthreads();
    size_t total = (size_t)M * 32;   // float4 count
    float4* o4 = (float4*)out;
    const float4* s4 = (const float4*)s_feats;
    for (size_t i = (size_t)blockIdx.x * 256 + t; i < total;
         i += (size_t)gridDim.x * 256) {
        float4 z = o4[i];
        float4 sf = s4[i];
        int c = ((int)(i & 31)) * 4;
        float v0 = z.x * a2s[c + 0] + b2s[c + 0] + sf.x;
        float v1 = z.y * a2s[c + 1] + b2s[c + 1] + sf.y;
        float v2 = z.z * a2s[c + 2] + b2s[c + 2] + sf.z;
        float v3 = z.w * a2s[c + 3] + b2s[c + 3] + sf.w;
        v0 = fmaxf(v0, NEG * v0); v1 = fmaxf(v1, NEG * v1);
        v2 = fmaxf(v2, NEG * v2); v3 = fmaxf(v3, NEG * v3);
        o4[i] = make_float4(v0, v1, v2, v3);
    }
}

extern "C" void kernel_launch(void* const* d_in, const int* in_sizes, int n_in,
                              void* d_out, int out_size, void* d_ws, size_t ws_size,
                              hipStream_t stream) {
    const float* q_pts   = (const float*)d_in[0];
    const float* s_pts   = (const float*)d_in[1];
    const float* s_feats = (const float*)d_in[2];
    const int*   idx     = (const int*)d_in[3];
    const float* kp      = (const float*)d_in[4];
    const float* w_u1    = (const float*)d_in[5];
    const float* g_u1    = (const float*)d_in[6];
    const float* b_u1    = (const float*)d_in[7];
    const float* w_g1    = (const float*)d_in[8];
    const float* b_g1    = (const float*)d_in[9];
    const float* w_g2    = (const float*)d_in[10];
    const float* b_g2    = (const float*)d_in[11];
    const float* g_c     = (const float*)d_in[12];
    const float* b_c     = (const float*)d_in[13];
    const float* w_u2    = (const float*)d_in[14];
    const float* g_u2    = (const float*)d_in[15];
    const float* b_u2    = (const float*)d_in[16];

    int M = in_sizes[3] / HNB;   // 50000

    float* ws = (float*)d_ws;
    float* y1  = ws;                         // M*32
    float* x2  = ws + (size_t)M * CMID;      // M*32
    float* st  = ws + (size_t)M * 2 * CMID;  // 384 (z-stats at [128:384))
    float* stb1 = st + 384;                  // 64 buckets x 64 (y1 stats)
    float* stb2 = stb1 + 64 * 64;            // 128 buckets x 64 (x2 stats)
    float* out = (float*)d_out;

    hipMemsetAsync(st, 0, (384 + 64 * 64 + 128 * 64) * sizeof(float), stream);

    int nbr = (M + 127) / 128;   // 391
    k1_gemm1<<<nbr, 256, 0, stream>>>(s_feats, w_u1, y1, stb1, M);
    k3_kpinv<<<(M + 7) / 8, 256, 0, stream>>>(y1, stb1, stb2, q_pts, s_pts, idx, kp,
                                              g_u1, b_u1, w_g1, b_g1, w_g2, b_g2,
                                              x2, M);
    k6_zstats<<<dim3(nbr, 4), 256, 0, stream>>>(x2, w_u2, g_c, b_c, stb2, st, out, M);
    k8_elem<<<2048, 256, 0, stream>>>(s_feats, g_u2, b_u2, st, out, M);
}

// Round 17
// 227.900 us; speedup vs baseline: 1.6522x; 1.0213x over previous
//
#include <hip/hip_runtime.h>

#define CMID 32
#define CIN 128
#define HNB 32
#define KP 15
#define NEG 0.1f
#define EPS 1e-5f
#define K3GRID 2048

// ---------------------------------------------------------------------------
// K1: y1 = s_feats @ w_u1 (M x 128 @ 128 x 32) + bucketed per-channel stats.
// Round-6-verified BM=128 body; stats to stb1 bucket (blockIdx&63).
// ---------------------------------------------------------------------------
__global__ __launch_bounds__(256) void k1_gemm1(
    const float* __restrict__ A, const float* __restrict__ B,
    float* __restrict__ y1, float* __restrict__ stb1, int M)
{
    __shared__ __align__(16) float AsT[32 * 128];  // 16 KB [j][row]
    __shared__ __align__(16) float Bs[128 * 32];   // 16 KB
    __shared__ __align__(16) float red[256];
    int t = threadIdx.x;
    for (int i = t; i < 128 * 32; i += 256) Bs[i] = B[i];

    int m0 = blockIdx.x * 128;
    int tx = t & 7, ty = t >> 3;
    int srow = t & 127, shh = t >> 7;
    float acc[4][4] = {{0.f}};

    for (int ch = 0; ch < 4; ++ch) {
        __syncthreads();
        int gr = m0 + srow;
        const float4* ap = (const float4*)(A + (size_t)gr * CIN + ch * 32 + shh * 16);
        float4 f0, f1, f2, f3;
        if (gr < M) { f0 = ap[0]; f1 = ap[1]; f2 = ap[2]; f3 = ap[3]; }
        else { f0 = f1 = f2 = f3 = make_float4(0.f, 0.f, 0.f, 0.f); }
        {
            int cb = shh * 16;
            AsT[(cb + 0) * 128 + srow] = f0.x;  AsT[(cb + 1) * 128 + srow] = f0.y;
            AsT[(cb + 2) * 128 + srow] = f0.z;  AsT[(cb + 3) * 128 + srow] = f0.w;
            AsT[(cb + 4) * 128 + srow] = f1.x;  AsT[(cb + 5) * 128 + srow] = f1.y;
            AsT[(cb + 6) * 128 + srow] = f1.z;  AsT[(cb + 7) * 128 + srow] = f1.w;
            AsT[(cb + 8) * 128 + srow] = f2.x;  AsT[(cb + 9) * 128 + srow] = f2.y;
            AsT[(cb + 10) * 128 + srow] = f2.z; AsT[(cb + 11) * 128 + srow] = f2.w;
            AsT[(cb + 12) * 128 + srow] = f3.x; AsT[(cb + 13) * 128 + srow] = f3.y;
            AsT[(cb + 14) * 128 + srow] = f3.z; AsT[(cb + 15) * 128 + srow] = f3.w;
        }
        __syncthreads();
        const float* bsp = Bs + (ch * 32) * 32 + tx * 4;
#pragma unroll
        for (int jl = 0; jl < 32; ++jl) {
            float4 av = *(const float4*)(AsT + jl * 128 + ty * 4);
            float4 bv = *(const float4*)(bsp + jl * 32);
            acc[0][0] += av.x * bv.x; acc[0][1] += av.x * bv.y; acc[0][2] += av.x * bv.z; acc[0][3] += av.x * bv.w;
            acc[1][0] += av.y * bv.x; acc[1][1] += av.y * bv.y; acc[1][2] += av.y * bv.z; acc[1][3] += av.y * bv.w;
            acc[2][0] += av.z * bv.x; acc[2][1] += av.z * bv.y; acc[2][2] += av.z * bv.z; acc[2][3] += av.z * bv.w;
            acc[3][0] += av.w * bv.x; acc[3][1] += av.w * bv.y; acc[3][2] += av.w * bv.z; acc[3][3] += av.w * bv.w;
        }
    }
#pragma unroll
    for (int i = 0; i < 4; ++i) {
        int r = m0 + ty * 4 + i;
        if (r < M)
            *(float4*)(y1 + (size_t)r * CMID + tx * 4) =
                make_float4(acc[i][0], acc[i][1], acc[i][2], acc[i][3]);
    }
    float s4[4], q4[4];
#pragma unroll
    for (int e = 0; e < 4; ++e) {
        s4[e] = acc[0][e] + acc[1][e] + acc[2][e] + acc[3][e];
        q4[e] = acc[0][e] * acc[0][e] + acc[1][e] * acc[1][e]
              + acc[2][e] * acc[2][e] + acc[3][e] * acc[3][e];
    }
#pragma unroll
    for (int off = 8; off <= 32; off <<= 1) {
#pragma unroll
        for (int e = 0; e < 4; ++e) {
            s4[e] += __shfl_xor(s4[e], off);
            q4[e] += __shfl_xor(q4[e], off);
        }
    }
    int lw = t >> 6, ll = t & 63;
    if (ll < 8) {
#pragma unroll
        for (int e = 0; e < 4; ++e) {
            red[(lw * 8 + ll) * 8 + e] = s4[e];
            red[(lw * 8 + ll) * 8 + 4 + e] = q4[e];
        }
    }
    __syncthreads();
    if (t < 64) {
        int tx2 = t >> 3, k = t & 7;
        float v = red[(0 * 8 + tx2) * 8 + k] + red[(1 * 8 + tx2) * 8 + k]
                + red[(2 * 8 + tx2) * 8 + k] + red[(3 * 8 + tx2) * 8 + k];
        int col = tx2 * 4 + (k & 3);
        atomicAdd(&stb1[(size_t)(blockIdx.x & 63) * 64 + (k < 4 ? 0 : 32) + col], v);
    }
}

// ---------------------------------------------------------------------------
// K3: KPInv conv, GRID-STRIDED at 2048 blocks: init (weights + bucket sum)
// runs once per block instead of once per 8 points (6250x); osum/osq
// accumulate in registers across iterations; single epilogue per block.
// vbuf/aux hazards across iterations are wave-private in-order DS (safe).
// ---------------------------------------------------------------------------
__global__ __launch_bounds__(256, 4) void k3_kpinv(
    const float* __restrict__ y1,
    const float* __restrict__ stb1, float* __restrict__ stb2,
    const float* __restrict__ q_pts, const float* __restrict__ s_pts,
    const int* __restrict__ idx, const float* __restrict__ kp,
    const float* __restrict__ g_u1, const float* __restrict__ b_u1,
    const float* __restrict__ w_g1, const float* __restrict__ b_g1,
    const float* __restrict__ w_g2, const float* __restrict__ b_g2,
    float* __restrict__ x2, int M)
{
    __shared__ __align__(16) float a1s[32], b1s[32];
    __shared__ __align__(16) float wg1[32 * 8];
    __shared__ __align__(16) float bg1[8];
    __shared__ __align__(16) float wg2[8 * 30];
    __shared__ __align__(16) float bg2[32];
    __shared__ __align__(16) float kps[KP * 3 + 1];
    __shared__ __align__(16) float vbuf[4][2][1024];
    __shared__ __align__(16) float aux[4][2][144];

    int t = threadIdx.x;
    // ---- init: sum k1's 64 stat buckets -> a1s/b1s (scratch: vbuf, aux) ----
    {
        float* tmp = &vbuf[0][0][0];
        int entry = t & 63, qd = t >> 6;
        float ps = 0.f;
        for (int b = qd * 16; b < qd * 16 + 16; ++b)
            ps += stb1[(size_t)b * 64 + entry];
        tmp[t] = ps;
        __syncthreads();
        if (t < 64)
            aux[0][0][t] = tmp[t] + tmp[64 + t] + tmp[128 + t] + tmp[192 + t];
        __syncthreads();
        if (t < 32) {
            float mean = aux[0][0][t] * (1.0f / M);
            float var  = aux[0][0][32 + t] * (1.0f / M) - mean * mean;
            float inv  = rsqrtf(var + EPS);
            float a = g_u1[t] * inv;
            a1s[t] = a;
            b1s[t] = b_u1[t] - mean * a;
        }
    }
    wg1[t & 255] = w_g1[t & 255];
    if (t < 8)   bg1[t] = b_g1[t];
    if (t < 240) wg2[t] = w_g2[t];
    if (t < 30)  bg2[t] = b_g2[t];
    else if (t < 32) bg2[t] = 0.f;
    if (t < KP * 3) kps[t] = kp[t];
    __syncthreads();

    int wave = t >> 6, lane = t & 63;
    int p = lane >> 5;
    int q = lane & 31;
    float* vb = &vbuf[wave][p][0];
    float* ax = &aux[wave][p][0];
    float osum = 0.f, osq = 0.f;
    int ng = (M + 7) / 8;

    for (int g = blockIdx.x; g < ng; g += K3GRID) {
        int m = g * 8 + wave * 2 + p;
        bool valid = (m < M);
        int mm = valid ? m : 0;

        // ---------------- Phase 1: q = h ----------------
        int h = q;
        int n = idx[(size_t)mm * HNB + h];
        float qx = q_pts[mm * 3 + 0], qy = q_pts[mm * 3 + 1], qz = q_pts[mm * 3 + 2];
        float dx = s_pts[n * 3 + 0] - qx;
        float dy = s_pts[n * 3 + 1] - qy;
        float dz = s_pts[n * 3 + 2] - qz;

        float infl[KP];
#pragma unroll
        for (int k = 0; k < KP; ++k) {
            float ex = dx - kps[k * 3 + 0];
            float ey = dy - kps[k * 3 + 1];
            float ez = dz - kps[k * 3 + 2];
            float d = sqrtf(ex * ex + ey * ey + ez * ez);
            infl[k] = fmaxf(1.0f - d, 0.f);
        }

        {
            const float4* row = (const float4*)(y1 + (size_t)n * CMID);
            int hq4 = h >> 2, h3 = h & 3;
#pragma unroll
            for (int jj = 0; jj < 8; ++jj) {
                float4 f = row[jj];
                float vv[4] = {f.x, f.y, f.z, f.w};
#pragma unroll
                for (int e = 0; e < 4; ++e) {
                    int c = jj * 4 + e;
                    float x = vv[e] * a1s[c] + b1s[c];
                    x = fmaxf(x, NEG * x);
                    vb[(c << 5) + ((hq4 ^ (c & 7)) << 2) + h3] = x;
                }
            }
        }
        __builtin_amdgcn_wave_barrier();

        // ---------------- Phase 2: q = c ----------------
        {
            int c = q;
            int c7 = c & 7;
            const float* vrow = vb + (c << 5);
            float cm = -1e30f;
#pragma unroll
            for (int j = 0; j < 8; ++j) {
                const float4 f = *(const float4*)(vrow + ((j ^ c7) << 2));
                cm = fmaxf(fmaxf(fmaxf(cm, f.x), fmaxf(f.y, f.z)), f.w);
            }
            ax[c] = cm;
            __builtin_amdgcn_wave_barrier();

            int jm = c & 7;
            float acc = bg1[jm];
#pragma unroll
            for (int cc = 0; cc < 8; ++cc) {
                const float4 ce = *(const float4*)(ax + (cc << 2));
                acc += ce.x * wg1[(cc * 4 + 0) * 8 + jm];
                acc += ce.y * wg1[(cc * 4 + 1) * 8 + jm];
                acc += ce.z * wg1[(cc * 4 + 2) * 8 + jm];
                acc += ce.w * wg1[(cc * 4 + 3) * 8 + jm];
            }
            float h1v = fmaxf(acc, NEG * acc);
            if (c < 8) ax[32 + c] = h1v;
            __builtin_amdgcn_wave_barrier();

            float wv = 0.f;
            if (c < 30) {
                const float4 ha = *(const float4*)(ax + 32);
                const float4 hb = *(const float4*)(ax + 36);
                wv = bg2[c]
                   + ha.x * wg2[0 * 30 + c] + ha.y * wg2[1 * 30 + c]
                   + ha.z * wg2[2 * 30 + c] + ha.w * wg2[3 * 30 + c]
                   + hb.x * wg2[4 * 30 + c] + hb.y * wg2[5 * 30 + c]
                   + hb.z * wg2[6 * 30 + c] + hb.w * wg2[7 * 30 + c];
            }
            ax[40 + c] = wv;
        }
        __builtin_amdgcn_wave_barrier();

        // ---------------- Phase 3: q = h ----------------
        {
            float wf[32];
#pragma unroll
            for (int j = 0; j < 8; ++j) {
                const float4 wc = *(const float4*)(ax + 40 + (j << 2));
                wf[j * 4 + 0] = wc.x; wf[j * 4 + 1] = wc.y;
                wf[j * 4 + 2] = wc.z; wf[j * 4 + 3] = wc.w;
            }
            float s0 = 0.f, s1 = 0.f;
#pragma unroll
            for (int k = 0; k < KP; ++k) {
                s0 += infl[k] * wf[2 * k + 0];
                s1 += infl[k] * wf[2 * k + 1];
            }
            ax[72 + q]  = s0;
            ax[104 + q] = s1;
        }
        __builtin_amdgcn_wave_barrier();

        // ---------------- Phase 4: q = c ----------------
        {
            int c = q;
            int c7 = c & 7;
            const float* sbuf = ax + 72 + ((c >> 4) << 5);
            const float* vrow = vb + (c << 5);
            float o = 0.f;
#pragma unroll
            for (int j = 0; j < 8; ++j) {
                const float4 vv = *(const float4*)(vrow + ((j ^ c7) << 2));
                const float4 ss = *(const float4*)(sbuf + (j << 2));
                o += vv.x * ss.x + vv.y * ss.y + vv.z * ss.z + vv.w * ss.w;
            }
            if (valid) {
                x2[(size_t)m * CMID + c] = o;
                osum += o;
                osq  += o * o;
            }
        }
        __builtin_amdgcn_wave_barrier();   // order phase-4 reads before next iter's writes
    }

    // ---- epilogue once per block: bucketed x2 stats ----
    __syncthreads();                   // all waves done with vbuf
    float* red = &vbuf[0][0][0];
    float* bkt = stb2 + (size_t)(blockIdx.x & 127) * 64;
    red[t] = osum;
    __syncthreads();
    if (t < 32) {
        float s = 0.f;
#pragma unroll
        for (int i = 0; i < 8; ++i) s += red[t + 32 * i];
        atomicAdd(&bkt[t], s);
    }
    __syncthreads();
    red[t] = osq;
    __syncthreads();
    if (t < 32) {
        float s = 0.f;
#pragma unroll
        for (int i = 0; i < 8; ++i) s += red[t + 32 * i];
        atomicAdd(&bkt[32 + t], s);
    }
}

// ---------------------------------------------------------------------------
// K6: z = lrelu(bn_c(x2)) @ w_u2; z -> out (scratch), z-stats -> st[128:384).
// Init sums k3's 128 x2-stat buckets (round-15/16 verified).
// ---------------------------------------------------------------------------
__global__ __launch_bounds__(256) void k6_zstats(
    const float* __restrict__ x2, const float* __restrict__ w_u2,
    const float* __restrict__ g_c, const float* __restrict__ b_c,
    const float* __restrict__ stb2, float* __restrict__ st,
    float* __restrict__ zout, int M)
{
    __shared__ __align__(16) float ST[32 * 128];
    __shared__ __align__(16) float Ws[32 * 32];
    __shared__ __align__(16) float acs[32], bcs[32];
    __shared__ __align__(16) float red[256];
    int t = threadIdx.x;
    int cb = blockIdx.y;
    int m0 = blockIdx.x * 128;
    for (int i = t; i < 32 * 32; i += 256)
        Ws[i] = w_u2[(i >> 5) * CIN + cb * 32 + (i & 31)];
    // ---- init: sum the 128 x2-stat buckets -> acs/bcs ----
    {
        int entry = t & 63, qd = t >> 6;
        float ps = 0.f;
        for (int b = qd * 32; b < qd * 32 + 32; ++b)
            ps += stb2[(size_t)b * 64 + entry];
        red[t] = ps;
        __syncthreads();
        if (t < 64)
            red[t] = red[t] + red[64 + t] + red[128 + t] + red[192 + t];
        __syncthreads();
        if (t < 32) {
            float mean = red[t] * (1.0f / M);
            float var  = red[32 + t] * (1.0f / M) - mean * mean;
            float inv  = rsqrtf(var + EPS);
            float a = g_c[t] * inv;
            acs[t] = a; bcs[t] = b_c[t] - mean * a;
        }
    }
    __syncthreads();

    int srow = t & 127, shh = t >> 7;
    int gr = m0 + srow;
    const float4* xp = (const float4*)(x2 + (size_t)gr * CMID + shh * 16);
    float4 f0, f1, f2, f3;
    if (gr < M) { f0 = xp[0]; f1 = xp[1]; f2 = xp[2]; f3 = xp[3]; }
    else { f0 = f1 = f2 = f3 = make_float4(0.f, 0.f, 0.f, 0.f); }
    {
        float vv[16] = {f0.x, f0.y, f0.z, f0.w, f1.x, f1.y, f1.z, f1.w,
                        f2.x, f2.y, f2.z, f2.w, f3.x, f3.y, f3.z, f3.w};
        int cbse = shh * 16;
#pragma unroll
        for (int e = 0; e < 16; ++e) {
            int c = cbse + e;
            float x = vv[e] * acs[c] + bcs[c];
            x = fmaxf(x, NEG * x);
            ST[c * 128 + srow] = (gr < M) ? x : 0.f;
        }
    }
    __syncthreads();

    int tx = t & 7, ty = t >> 3;
    float acc[4][4] = {{0.f}};
#pragma unroll
    for (int j = 0; j < 32; ++j) {
        float4 av = *(const float4*)(ST + j * 128 + ty * 4);
        float4 bv = *(const float4*)(Ws + j * 32 + tx * 4);
        acc[0][0] += av.x * bv.x; acc[0][1] += av.x * bv.y; acc[0][2] += av.x * bv.z; acc[0][3] += av.x * bv.w;
        acc[1][0] += av.y * bv.x; acc[1][1] += av.y * bv.y; acc[1][2] += av.y * bv.z; acc[1][3] += av.y * bv.w;
        acc[2][0] += av.z * bv.x; acc[2][1] += av.z * bv.y; acc[2][2] += av.z * bv.z; acc[2][3] += av.z * bv.w;
        acc[3][0] += av.w * bv.x; acc[3][1] += av.w * bv.y; acc[3][2] += av.w * bv.z; acc[3][3] += av.w * bv.w;
    }
    // store z (scratch in out buffer)
#pragma unroll
    for (int i = 0; i < 4; ++i) {
        int r = m0 + ty * 4 + i;
        if (r < M)
            *(float4*)(zout + (size_t)r * CIN + cb * 32 + tx * 4) =
                make_float4(acc[i][0], acc[i][1], acc[i][2], acc[i][3]);
    }
    // z-stats (plain atomics: 1564 blocks / 256 addrs = ~6 chains/addr, fine)
    float s4[4], q4[4];
#pragma unroll
    for (int e = 0; e < 4; ++e) {
        s4[e] = acc[0][e] + acc[1][e] + acc[2][e] + acc[3][e];
        q4[e] = acc[0][e] * acc[0][e] + acc[1][e] * acc[1][e]
              + acc[2][e] * acc[2][e] + acc[3][e] * acc[3][e];
    }
#pragma unroll
    for (int off = 8; off <= 32; off <<= 1) {
#pragma unroll
        for (int e = 0; e < 4; ++e) {
            s4[e] += __shfl_xor(s4[e], off);
            q4[e] += __shfl_xor(q4[e], off);
        }
    }
    int lw = t >> 6, ll = t & 63;
    if (ll < 8) {
#pragma unroll
        for (int e = 0; e < 4; ++e) {
            red[(lw * 8 + ll) * 8 + e] = s4[e];
            red[(lw * 8 + ll) * 8 + 4 + e] = q4[e];
        }
    }
    __syncthreads();
    if (t < 64) {
        int tx2 = t >> 3, k = t & 7;
        float v = red[(0 * 8 + tx2) * 8 + k] + red[(1 * 8 + tx2) * 8 + k]
                + red[(2 * 8 + tx2) * 8 + k] + red[(3 * 8 + tx2) * 8 + k];
        int col = cb * 32 + tx2 * 4 + (k & 3);
        atomicAdd(&st[(k < 4 ? 128 : 256) + col], v);
    }
}

// ---------------------------------------------------------------------------
// K8: elementwise final. z in out (scratch): out = lrelu(z*a2+b2 + s_feats).
// ---------------------------------------------------------------------------
__global__ __launch_bounds__(256) void k8_elem(
    const float* __restrict__ s_feats,
    const float* __restrict__ g_u2, const float* __restrict__ b_u2,
    const float* __restrict__ st, float* __restrict__ out, int M)
{
    __shared__ float a2s[128], b2s[128];
    int t = threadIdx.x;
    if (t < 128) {
        float mean = st[128 + t] * (1.0f / M);
        float var  = st[256 + t] * (1.0f / M) - mean * mean;
        float inv  = rsqrtf(var + EPS);
        float a = g_u2[t] * inv;
        a2s[t] = a; b2s[t] = b_u2[t] - mean * a;
    }
    __syncthreads();
    size_t total = (size_t)M * 32;   // float4 count
    float4* o4 = (float4*)out;
    const float4* s4 = (const float4*)s_feats;
    for (size_t i = (size_t)blockIdx.x * 256 + t; i < total;
         i += (size_t)gridDim.x * 256) {
        float4 z = o4[i];
        float4 sf = s4[i];
        int c = ((int)(i & 31)) * 4;
        float v0 = z.x * a2s[c + 0] + b2s[c + 0] + sf.x;
        float v1 = z.y * a2s[c + 1] + b2s[c + 1] + sf.y;
        float v2 = z.z * a2s[c + 2] + b2s[c + 2] + sf.z;
        float v3 = z.w * a2s[c + 3] + b2s[c + 3] + sf.w;
        v0 = fmaxf(v0, NEG * v0); v1 = fmaxf(v1, NEG * v1);
        v2 = fmaxf(v2, NEG * v2); v3 = fmaxf(v3, NEG * v3);
        o4[i] = make_float4(v0, v1, v2, v3);
    }
}

extern "C" void kernel_launch(void* const* d_in, const int* in_sizes, int n_in,
                              void* d_out, int out_size, void* d_ws, size_t ws_size,
                              hipStream_t stream) {
    const float* q_pts   = (const float*)d_in[0];
    const float* s_pts   = (const float*)d_in[1];
    const float* s_feats = (const float*)d_in[2];
    const int*   idx     = (const int*)d_in[3];
    const float* kp      = (const float*)d_in[4];
    const float* w_u1    = (const float*)d_in[5];
    const float* g_u1    = (const float*)d_in[6];
    const float* b_u1    = (const float*)d_in[7];
    const float* w_g1    = (const float*)d_in[8];
    const float* b_g1    = (const float*)d_in[9];
    const float* w_g2    = (const float*)d_in[10];
    const float* b_g2    = (const float*)d_in[11];
    const float* g_c     = (const float*)d_in[12];
    const float* b_c     = (const float*)d_in[13];
    const float* w_u2    = (const float*)d_in[14];
    const float* g_u2    = (const float*)d_in[15];
    const float* b_u2    = (const float*)d_in[16];

    int M = in_sizes[3] / HNB;   // 50000

    float* ws = (float*)d_ws;
    float* y1  = ws;                         // M*32
    float* x2  = ws + (size_t)M * CMID;      // M*32
    float* st  = ws + (size_t)M * 2 * CMID;  // 384 (z-stats at [128:384))
    float* stb1 = st + 384;                  // 64 buckets x 64 (y1 stats)
    float* stb2 = stb1 + 64 * 64;            // 128 buckets x 64 (x2 stats)
    float* out = (float*)d_out;

    hipMemsetAsync(st, 0, (384 + 64 * 64 + 128 * 64) * sizeof(float), stream);

    int nbr = (M + 127) / 128;   // 391
    k1_gemm1<<<nbr, 256, 0, stream>>>(s_feats, w_u1, y1, stb1, M);
    k3_kpinv<<<K3GRID, 256, 0, stream>>>(y1, stb1, stb2, q_pts, s_pts, idx, kp,
                                         g_u1, b_u1, w_g1, b_g1, w_g2, b_g2,
                                         x2, M);
    k6_zstats<<<dim3(nbr, 4), 256, 0, stream>>>(x2, w_u2, g_c, b_c, stb2, st, out, M);
    k8_elem<<<2048, 256, 0, stream>>>(s_feats, g_u2, b_u2, st, out, M);
}

// Round 18
// 225.801 us; speedup vs baseline: 1.6676x; 1.0093x over previous
//
#include <hip/hip_runtime.h>

#define CMID 32
#define CIN 128
#define HNB 32
#define KP 15
#define NEG 0.1f
#define EPS 1e-5f
#define K3GRID 2048

// ---------------------------------------------------------------------------
// K1: y1 = s_feats @ w_u1 (M x 128 @ 128 x 32) + bucketed per-channel stats.
// Round-6-verified BM=128 body; stats to stb1 bucket (blockIdx&63).
// ---------------------------------------------------------------------------
__global__ __launch_bounds__(256) void k1_gemm1(
    const float* __restrict__ A, const float* __restrict__ B,
    float* __restrict__ y1, float* __restrict__ stb1, int M)
{
    __shared__ __align__(16) float AsT[32 * 128];  // 16 KB [j][row]
    __shared__ __align__(16) float Bs[128 * 32];   // 16 KB
    __shared__ __align__(16) float red[256];
    int t = threadIdx.x;
    for (int i = t; i < 128 * 32; i += 256) Bs[i] = B[i];

    int m0 = blockIdx.x * 128;
    int tx = t & 7, ty = t >> 3;
    int srow = t & 127, shh = t >> 7;
    float acc[4][4] = {{0.f}};

    for (int ch = 0; ch < 4; ++ch) {
        __syncthreads();
        int gr = m0 + srow;
        const float4* ap = (const float4*)(A + (size_t)gr * CIN + ch * 32 + shh * 16);
        float4 f0, f1, f2, f3;
        if (gr < M) { f0 = ap[0]; f1 = ap[1]; f2 = ap[2]; f3 = ap[3]; }
        else { f0 = f1 = f2 = f3 = make_float4(0.f, 0.f, 0.f, 0.f); }
        {
            int cb = shh * 16;
            AsT[(cb + 0) * 128 + srow] = f0.x;  AsT[(cb + 1) * 128 + srow] = f0.y;
            AsT[(cb + 2) * 128 + srow] = f0.z;  AsT[(cb + 3) * 128 + srow] = f0.w;
            AsT[(cb + 4) * 128 + srow] = f1.x;  AsT[(cb + 5) * 128 + srow] = f1.y;
            AsT[(cb + 6) * 128 + srow] = f1.z;  AsT[(cb + 7) * 128 + srow] = f1.w;
            AsT[(cb + 8) * 128 + srow] = f2.x;  AsT[(cb + 9) * 128 + srow] = f2.y;
            AsT[(cb + 10) * 128 + srow] = f2.z; AsT[(cb + 11) * 128 + srow] = f2.w;
            AsT[(cb + 12) * 128 + srow] = f3.x; AsT[(cb + 13) * 128 + srow] = f3.y;
            AsT[(cb + 14) * 128 + srow] = f3.z; AsT[(cb + 15) * 128 + srow] = f3.w;
        }
        __syncthreads();
        const float* bsp = Bs + (ch * 32) * 32 + tx * 4;
#pragma unroll
        for (int jl = 0; jl < 32; ++jl) {
            float4 av = *(const float4*)(AsT + jl * 128 + ty * 4);
            float4 bv = *(const float4*)(bsp + jl * 32);
            acc[0][0] += av.x * bv.x; acc[0][1] += av.x * bv.y; acc[0][2] += av.x * bv.z; acc[0][3] += av.x * bv.w;
            acc[1][0] += av.y * bv.x; acc[1][1] += av.y * bv.y; acc[1][2] += av.y * bv.z; acc[1][3] += av.y * bv.w;
            acc[2][0] += av.z * bv.x; acc[2][1] += av.z * bv.y; acc[2][2] += av.z * bv.z; acc[2][3] += av.z * bv.w;
            acc[3][0] += av.w * bv.x; acc[3][1] += av.w * bv.y; acc[3][2] += av.w * bv.z; acc[3][3] += av.w * bv.w;
        }
    }
#pragma unroll
    for (int i = 0; i < 4; ++i) {
        int r = m0 + ty * 4 + i;
        if (r < M)
            *(float4*)(y1 + (size_t)r * CMID + tx * 4) =
                make_float4(acc[i][0], acc[i][1], acc[i][2], acc[i][3]);
    }
    float s4[4], q4[4];
#pragma unroll
    for (int e = 0; e < 4; ++e) {
        s4[e] = acc[0][e] + acc[1][e] + acc[2][e] + acc[3][e];
        q4[e] = acc[0][e] * acc[0][e] + acc[1][e] * acc[1][e]
              + acc[2][e] * acc[2][e] + acc[3][e] * acc[3][e];
    }
#pragma unroll
    for (int off = 8; off <= 32; off <<= 1) {
#pragma unroll
        for (int e = 0; e < 4; ++e) {
            s4[e] += __shfl_xor(s4[e], off);
            q4[e] += __shfl_xor(q4[e], off);
        }
    }
    int lw = t >> 6, ll = t & 63;
    if (ll < 8) {
#pragma unroll
        for (int e = 0; e < 4; ++e) {
            red[(lw * 8 + ll) * 8 + e] = s4[e];
            red[(lw * 8 + ll) * 8 + 4 + e] = q4[e];
        }
    }
    __syncthreads();
    if (t < 64) {
        int tx2 = t >> 3, k = t & 7;
        float v = red[(0 * 8 + tx2) * 8 + k] + red[(1 * 8 + tx2) * 8 + k]
                + red[(2 * 8 + tx2) * 8 + k] + red[(3 * 8 + tx2) * 8 + k];
        int col = tx2 * 4 + (k & 3);
        atomicAdd(&stb1[(size_t)(blockIdx.x & 63) * 64 + (k < 4 ? 0 : 32) + col], v);
    }
}

// ---------------------------------------------------------------------------
// K3: KPInv conv, grid-strided + NEXT-ITERATION idx/q_pts PREFETCH.
// Each iteration's critical path starts with the idx load; prefetching it
// during the current iteration's gather phase removes that serial link for
// all but the first iteration (~3 iters/block at K3GRID=2048).
// ---------------------------------------------------------------------------
__global__ __launch_bounds__(256, 4) void k3_kpinv(
    const float* __restrict__ y1,
    const float* __restrict__ stb1, float* __restrict__ stb2,
    const float* __restrict__ q_pts, const float* __restrict__ s_pts,
    const int* __restrict__ idx, const float* __restrict__ kp,
    const float* __restrict__ g_u1, const float* __restrict__ b_u1,
    const float* __restrict__ w_g1, const float* __restrict__ b_g1,
    const float* __restrict__ w_g2, const float* __restrict__ b_g2,
    float* __restrict__ x2, int M)
{
    __shared__ __align__(16) float a1s[32], b1s[32];
    __shared__ __align__(16) float wg1[32 * 8];
    __shared__ __align__(16) float bg1[8];
    __shared__ __align__(16) float wg2[8 * 30];
    __shared__ __align__(16) float bg2[32];
    __shared__ __align__(16) float kps[KP * 3 + 1];
    __shared__ __align__(16) float vbuf[4][2][1024];
    __shared__ __align__(16) float aux[4][2][144];

    int t = threadIdx.x;
    // ---- init: sum k1's 64 stat buckets -> a1s/b1s (scratch: vbuf, aux) ----
    {
        float* tmp = &vbuf[0][0][0];
        int entry = t & 63, qd = t >> 6;
        float ps = 0.f;
        for (int b = qd * 16; b < qd * 16 + 16; ++b)
            ps += stb1[(size_t)b * 64 + entry];
        tmp[t] = ps;
        __syncthreads();
        if (t < 64)
            aux[0][0][t] = tmp[t] + tmp[64 + t] + tmp[128 + t] + tmp[192 + t];
        __syncthreads();
        if (t < 32) {
            float mean = aux[0][0][t] * (1.0f / M);
            float var  = aux[0][0][32 + t] * (1.0f / M) - mean * mean;
            float inv  = rsqrtf(var + EPS);
            float a = g_u1[t] * inv;
            a1s[t] = a;
            b1s[t] = b_u1[t] - mean * a;
        }
    }
    wg1[t & 255] = w_g1[t & 255];
    if (t < 8)   bg1[t] = b_g1[t];
    if (t < 240) wg2[t] = w_g2[t];
    if (t < 30)  bg2[t] = b_g2[t];
    else if (t < 32) bg2[t] = 0.f;
    if (t < KP * 3) kps[t] = kp[t];
    __syncthreads();

    int wave = t >> 6, lane = t & 63;
    int p = lane >> 5;
    int q = lane & 31;
    int h = q;
    float* vb = &vbuf[wave][p][0];
    float* ax = &aux[wave][p][0];
    float osum = 0.f, osq = 0.f;
    int ng = (M + 7) / 8;

    // preload iteration blockIdx.x
    int n; float qx, qy, qz;
    {
        int m0i = blockIdx.x * 8 + wave * 2 + p;
        int mm = (m0i < M) ? m0i : 0;
        n  = idx[(size_t)mm * HNB + h];
        qx = q_pts[mm * 3 + 0]; qy = q_pts[mm * 3 + 1]; qz = q_pts[mm * 3 + 2];
    }

    for (int g = blockIdx.x; g < ng; g += K3GRID) {
        int m = g * 8 + wave * 2 + p;
        bool valid = (m < M);

        // ---------------- Phase 1: q = h ----------------
        float dx = s_pts[n * 3 + 0] - qx;
        float dy = s_pts[n * 3 + 1] - qy;
        float dz = s_pts[n * 3 + 2] - qz;

        float infl[KP];
#pragma unroll
        for (int k = 0; k < KP; ++k) {
            float ex = dx - kps[k * 3 + 0];
            float ey = dy - kps[k * 3 + 1];
            float ez = dz - kps[k * 3 + 2];
            float d = sqrtf(ex * ex + ey * ey + ez * ez);
            infl[k] = fmaxf(1.0f - d, 0.f);
        }

        // prefetch next iteration's idx + q_pts (hides their latency under
        // the gather + phases 2-4)
        int n_nx = n; float qx_nx = qx, qy_nx = qy, qz_nx = qz;
        {
            int gn = g + K3GRID;
            if (gn < ng) {
                int nm = gn * 8 + wave * 2 + p;
                int nmm = (nm < M) ? nm : 0;
                n_nx  = idx[(size_t)nmm * HNB + h];
                qx_nx = q_pts[nmm * 3 + 0];
                qy_nx = q_pts[nmm * 3 + 1];
                qz_nx = q_pts[nmm * 3 + 2];
            }
        }

        {
            const float4* row = (const float4*)(y1 + (size_t)n * CMID);
            int hq4 = h >> 2, h3 = h & 3;
#pragma unroll
            for (int jj = 0; jj < 8; ++jj) {
                float4 f = row[jj];
                float vv[4] = {f.x, f.y, f.z, f.w};
#pragma unroll
                for (int e = 0; e < 4; ++e) {
                    int c = jj * 4 + e;
                    float x = vv[e] * a1s[c] + b1s[c];
                    x = fmaxf(x, NEG * x);
                    vb[(c << 5) + ((hq4 ^ (c & 7)) << 2) + h3] = x;
                }
            }
        }
        __builtin_amdgcn_wave_barrier();

        // ---------------- Phase 2: q = c ----------------
        {
            int c = q;
            int c7 = c & 7;
            const float* vrow = vb + (c << 5);
            float cm = -1e30f;
#pragma unroll
            for (int j = 0; j < 8; ++j) {
                const float4 f = *(const float4*)(vrow + ((j ^ c7) << 2));
                cm = fmaxf(fmaxf(fmaxf(cm, f.x), fmaxf(f.y, f.z)), f.w);
            }
            ax[c] = cm;
            __builtin_amdgcn_wave_barrier();

            int jm = c & 7;
            float acc = bg1[jm];
#pragma unroll
            for (int cc = 0; cc < 8; ++cc) {
                const float4 ce = *(const float4*)(ax + (cc << 2));
                acc += ce.x * wg1[(cc * 4 + 0) * 8 + jm];
                acc += ce.y * wg1[(cc * 4 + 1) * 8 + jm];
                acc += ce.z * wg1[(cc * 4 + 2) * 8 + jm];
                acc += ce.w * wg1[(cc * 4 + 3) * 8 + jm];
            }
            float h1v = fmaxf(acc, NEG * acc);
            if (c < 8) ax[32 + c] = h1v;
            __builtin_amdgcn_wave_barrier();

            float wv = 0.f;
            if (c < 30) {
                const float4 ha = *(const float4*)(ax + 32);
                const float4 hb = *(const float4*)(ax + 36);
                wv = bg2[c]
                   + ha.x * wg2[0 * 30 + c] + ha.y * wg2[1 * 30 + c]
                   + ha.z * wg2[2 * 30 + c] + ha.w * wg2[3 * 30 + c]
                   + hb.x * wg2[4 * 30 + c] + hb.y * wg2[5 * 30 + c]
                   + hb.z * wg2[6 * 30 + c] + hb.w * wg2[7 * 30 + c];
            }
            ax[40 + c] = wv;
        }
        __builtin_amdgcn_wave_barrier();

        // ---------------- Phase 3: q = h ----------------
        {
            float wf[32];
#pragma unroll
            for (int j = 0; j < 8; ++j) {
                const float4 wc = *(const float4*)(ax + 40 + (j << 2));
                wf[j * 4 + 0] = wc.x; wf[j * 4 + 1] = wc.y;
                wf[j * 4 + 2] = wc.z; wf[j * 4 + 3] = wc.w;
            }
            float s0 = 0.f, s1 = 0.f;
#pragma unroll
            for (int k = 0; k < KP; ++k) {
                s0 += infl[k] * wf[2 * k + 0];
                s1 += infl[k] * wf[2 * k + 1];
            }
            ax[72 + q]  = s0;
            ax[104 + q] = s1;
        }
        __builtin_amdgcn_wave_barrier();

        // ---------------- Phase 4: q = c ----------------
        {
            int c = q;
            int c7 = c & 7;
            const float* sbuf = ax + 72 + ((c >> 4) << 5);
            const float* vrow = vb + (c << 5);
            float o = 0.f;
#pragma unroll
            for (int j = 0; j < 8; ++j) {
                const float4 vv = *(const float4*)(vrow + ((j ^ c7) << 2));
                const float4 ss = *(const float4*)(sbuf + (j << 2));
                o += vv.x * ss.x + vv.y * ss.y + vv.z * ss.z + vv.w * ss.w;
            }
            if (valid) {
                x2[(size_t)m * CMID + c] = o;
                osum += o;
                osq  += o * o;
            }
        }
        __builtin_amdgcn_wave_barrier();   // order phase-4 reads before next iter's writes

        n = n_nx; qx = qx_nx; qy = qy_nx; qz = qz_nx;
    }

    // ---- epilogue once per block: bucketed x2 stats ----
    __syncthreads();                   // all waves done with vbuf
    float* red = &vbuf[0][0][0];
    float* bkt = stb2 + (size_t)(blockIdx.x & 127) * 64;
    red[t] = osum;
    __syncthreads();
    if (t < 32) {
        float s = 0.f;
#pragma unroll
        for (int i = 0; i < 8; ++i) s += red[t + 32 * i];
        atomicAdd(&bkt[t], s);
    }
    __syncthreads();
    red[t] = osq;
    __syncthreads();
    if (t < 32) {
        float s = 0.f;
#pragma unroll
        for (int i = 0; i < 8; ++i) s += red[t + 32 * i];
        atomicAdd(&bkt[32 + t], s);
    }
}

// ---------------------------------------------------------------------------
// K6: z = lrelu(bn_c(x2)) @ w_u2; z -> out (scratch), z-stats -> st[128:384).
// Column split 4 -> 2: each block stages ST once and runs TWO w_u2 column
// slices (cb = blockIdx.y*2 + {0,1}), halving redundant x2 re-read/staging
// while keeping 782 blocks (>=3/CU TLP).
// ---------------------------------------------------------------------------
__global__ __launch_bounds__(256) void k6_zstats(
    const float* __restrict__ x2, const float* __restrict__ w_u2,
    const float* __restrict__ g_c, const float* __restrict__ b_c,
    const float* __restrict__ stb2, float* __restrict__ st,
    float* __restrict__ zout, int M)
{
    __shared__ __align__(16) float ST[32 * 128];
    __shared__ __align__(16) float Ws[32 * 32];
    __shared__ __align__(16) float acs[32], bcs[32];
    __shared__ __align__(16) float red[256];
    int t = threadIdx.x;
    int m0 = blockIdx.x * 128;
    // ---- init: sum the 128 x2-stat buckets -> acs/bcs ----
    {
        int entry = t & 63, qd = t >> 6;
        float ps = 0.f;
        for (int b = qd * 32; b < qd * 32 + 32; ++b)
            ps += stb2[(size_t)b * 64 + entry];
        red[t] = ps;
        __syncthreads();
        if (t < 64)
            red[t] = red[t] + red[64 + t] + red[128 + t] + red[192 + t];
        __syncthreads();
        if (t < 32) {
            float mean = red[t] * (1.0f / M);
            float var  = red[32 + t] * (1.0f / M) - mean * mean;
            float inv  = rsqrtf(var + EPS);
            float a = g_c[t] * inv;
            acs[t] = a; bcs[t] = b_c[t] - mean * a;
        }
    }
    __syncthreads();

    // stage ST once
    int srow = t & 127, shh = t >> 7;
    int gr = m0 + srow;
    const float4* xp = (const float4*)(x2 + (size_t)gr * CMID + shh * 16);
    float4 f0, f1, f2, f3;
    if (gr < M) { f0 = xp[0]; f1 = xp[1]; f2 = xp[2]; f3 = xp[3]; }
    else { f0 = f1 = f2 = f3 = make_float4(0.f, 0.f, 0.f, 0.f); }
    {
        float vv[16] = {f0.x, f0.y, f0.z, f0.w, f1.x, f1.y, f1.z, f1.w,
                        f2.x, f2.y, f2.z, f2.w, f3.x, f3.y, f3.z, f3.w};
        int cbse = shh * 16;
#pragma unroll
        for (int e = 0; e < 16; ++e) {
            int c = cbse + e;
            float x = vv[e] * acs[c] + bcs[c];
            x = fmaxf(x, NEG * x);
            ST[c * 128 + srow] = (gr < M) ? x : 0.f;
        }
    }

    int tx = t & 7, ty = t >> 3;
#pragma unroll
    for (int sl = 0; sl < 2; ++sl) {
        int cb = blockIdx.y * 2 + sl;
        __syncthreads();    // previous pass done with Ws/red (and ST staged)
        for (int i = t; i < 32 * 32; i += 256)
            Ws[i] = w_u2[(i >> 5) * CIN + cb * 32 + (i & 31)];
        __syncthreads();

        float acc[4][4] = {{0.f}};
#pragma unroll
        for (int j = 0; j < 32; ++j) {
            float4 av = *(const float4*)(ST + j * 128 + ty * 4);
            float4 bv = *(const float4*)(Ws + j * 32 + tx * 4);
            acc[0][0] += av.x * bv.x; acc[0][1] += av.x * bv.y; acc[0][2] += av.x * bv.z; acc[0][3] += av.x * bv.w;
            acc[1][0] += av.y * bv.x; acc[1][1] += av.y * bv.y; acc[1][2] += av.y * bv.z; acc[1][3] += av.y * bv.w;
            acc[2][0] += av.z * bv.x; acc[2][1] += av.z * bv.y; acc[2][2] += av.z * bv.z; acc[2][3] += av.z * bv.w;
            acc[3][0] += av.w * bv.x; acc[3][1] += av.w * bv.y; acc[3][2] += av.w * bv.z; acc[3][3] += av.w * bv.w;
        }
        // store z (scratch in out buffer)
#pragma unroll
        for (int i = 0; i < 4; ++i) {
            int r = m0 + ty * 4 + i;
            if (r < M)
                *(float4*)(zout + (size_t)r * CIN + cb * 32 + tx * 4) =
                    make_float4(acc[i][0], acc[i][1], acc[i][2], acc[i][3]);
        }
        // z-stats for this slice
        float s4[4], q4[4];
#pragma unroll
        for (int e = 0; e < 4; ++e) {
            s4[e] = acc[0][e] + acc[1][e] + acc[2][e] + acc[3][e];
            q4[e] = acc[0][e] * acc[0][e] + acc[1][e] * acc[1][e]
                  + acc[2][e] * acc[2][e] + acc[3][e] * acc[3][e];
        }
#pragma unroll
        for (int off = 8; off <= 32; off <<= 1) {
#pragma unroll
            for (int e = 0; e < 4; ++e) {
                s4[e] += __shfl_xor(s4[e], off);
                q4[e] += __shfl_xor(q4[e], off);
            }
        }
        int lw = t >> 6, ll = t & 63;
        __syncthreads();    // red free (init/previous pass done)
        if (ll < 8) {
#pragma unroll
            for (int e = 0; e < 4; ++e) {
                red[(lw * 8 + ll) * 8 + e] = s4[e];
                red[(lw * 8 + ll) * 8 + 4 + e] = q4[e];
            }
        }
        __syncthreads();
        if (t < 64) {
            int tx2 = t >> 3, k = t & 7;
            float v = red[(0 * 8 + tx2) * 8 + k] + red[(1 * 8 + tx2) * 8 + k]
                    + red[(2 * 8 + tx2) * 8 + k] + red[(3 * 8 + tx2) * 8 + k];
            int col = cb * 32 + tx2 * 4 + (k & 3);
            atomicAdd(&st[(k < 4 ? 128 : 256) + col], v);
        }
    }
}

// ---------------------------------------------------------------------------
// K8: elementwise final. z in out (scratch): out = lrelu(z*a2+b2 + s_feats).
// ---------------------------------------------------------------------------
__global__ __launch_bounds__(256) void k8_elem(
    const float* __restrict__ s_feats,
    const float* __restrict__ g_u2, const float* __restrict__ b_u2,
    const float* __restrict__ st, float* __restrict__ out, int M)
{
    __shared__ float a2s[128], b2s[128];
    int t = threadIdx.x;
    if (t < 128) {
        float mean = st[128 + t] * (1.0f / M);
        float var  = st[256 + t] * (1.0f / M) - mean * mean;
        float inv  = rsqrtf(var + EPS);
        float a = g_u2[t] * inv;
        a2s[t] = a; b2s[t] = b_u2[t] - mean * a;
    }
    __syncthreads();
    size_t total = (size_t)M * 32;   // float4 count
    float4* o4 = (float4*)out;
    const float4* s4 = (const float4*)s_feats;
    for (size_t i = (size_t)blockIdx.x * 256 + t; i < total;
         i += (size_t)gridDim.x * 256) {
        float4 z = o4[i];
        float4 sf = s4[i];
        int c = ((int)(i & 31)) * 4;
        float v0 = z.x * a2s[c + 0] + b2s[c + 0] + sf.x;
        float v1 = z.y * a2s[c + 1] + b2s[c + 1] + sf.y;
        float v2 = z.z * a2s[c + 2] + b2s[c + 2] + sf.z;
        float v3 = z.w * a2s[c + 3] + b2s[c + 3] + sf.w;
        v0 = fmaxf(v0, NEG * v0); v1 = fmaxf(v1, NEG * v1);
        v2 = fmaxf(v2, NEG * v2); v3 = fmaxf(v3, NEG * v3);
        o4[i] = make_float4(v0, v1, v2, v3);
    }
}

extern "C" void kernel_launch(void* const* d_in, const int* in_sizes, int n_in,
                              void* d_out, int out_size, void* d_ws, size_t ws_size,
                              hipStream_t stream) {
    const float* q_pts   = (const float*)d_in[0];
    const float* s_pts   = (const float*)d_in[1];
    const float* s_feats = (const float*)d_in[2];
    const int*   idx     = (const int*)d_in[3];
    const float* kp      = (const float*)d_in[4];
    const float* w_u1    = (const float*)d_in[5];
    const float* g_u1    = (const float*)d_in[6];
    const float* b_u1    = (const float*)d_in[7];
    const float* w_g1    = (const float*)d_in[8];
    const float* b_g1    = (const float*)d_in[9];
    const float* w_g2    = (const float*)d_in[10];
    const float* b_g2    = (const float*)d_in[11];
    const float* g_c     = (const float*)d_in[12];
    const float* b_c     = (const float*)d_in[13];
    const float* w_u2    = (const float*)d_in[14];
    const float* g_u2    = (const float*)d_in[15];
    const float* b_u2    = (const float*)d_in[16];

    int M = in_sizes[3] / HNB;   // 50000

    float* ws = (float*)d_ws;
    float* y1  = ws;                         // M*32
    float* x2  = ws + (size_t)M * CMID;      // M*32
    float* st  = ws + (size_t)M * 2 * CMID;  // 384 (z-stats at [128:384))
    float* stb1 = st + 384;                  // 64 buckets x 64 (y1 stats)
    float* stb2 = stb1 + 64 * 64;            // 128 buckets x 64 (x2 stats)
    float* out = (float*)d_out;

    hipMemsetAsync(st, 0, (384 + 64 * 64 + 128 * 64) * sizeof(float), stream);

    int nbr = (M + 127) / 128;   // 391
    k1_gemm1<<<nbr, 256, 0, stream>>>(s_feats, w_u1, y1, stb1, M);
    k3_kpinv<<<K3GRID, 256, 0, stream>>>(y1, stb1, stb2, q_pts, s_pts, idx, kp,
                                         g_u1, b_u1, w_g1, b_g1, w_g2, b_g2,
                                         x2, M);
    k6_zstats<<<dim3(nbr, 2), 256, 0, stream>>>(x2, w_u2, g_c, b_c, stb2, st, out, M);
    k8_elem<<<2048, 256, 0, stream>>>(s_feats, g_u2, b_u2, st, out, M);
}